// Round 3
// baseline (2762.352 us; speedup 1.0000x reference)
//
#include <hip/hip_runtime.h>
#include <math.h>

typedef _Float16 f16;
typedef f16 f16x8 __attribute__((ext_vector_type(8)));
typedef float f32x4 __attribute__((ext_vector_type(4)));

#define NTOT 3840
#define KP   3968          // 3840 neurons + 128 inputs
#define BATCH 32
#define TSTEPS 100
#define NIN 128

__device__ __forceinline__ bool is_dend(int k){
  return (k>=512 && k<1536) || (k>=2432 && k<3456);
}
__device__ __forceinline__ bool is_inh(int k){
  return (k>=1536 && k<1920) || (k>=3456 && k<3840);
}
__device__ __forceinline__ ushort f2h(float v){ f16 h=(f16)v; return *(ushort*)&h; }
__device__ __forceinline__ float h2f(ushort u){ f16 h=*(f16*)&u; return (float)h; }

// ---------- one-time: WT[n][k] = fp16(w_eff^T), mask derived analytically ----------
__global__ __launch_bounds__(256) void k_prep_w(const float* __restrict__ w_rec,
    const float* __restrict__ w_in, ushort* __restrict__ WT){
  __shared__ ushort tile[64][72];
  const int bid = blockIdx.x;
  const int kt = bid / 60, nt = bid % 60;
  const int k0 = kt*64, n0 = nt*64;
  const int t = threadIdx.x;
  const int tr = t>>2, tq = t&3;
  const int k = k0 + tr;
  const int cbase = n0 + tq*16;
  if (k < NTOT){
    const float sgn = is_inh(k) ? -1.f : 1.f;
    const bool rowSr  = (k>=512  && k<1536);
    const bool rowPfc = (k>=2432 && k<3456);
    #pragma unroll
    for (int q=0;q<4;q++){
      float4 w = *(const float4*)(w_rec + (size_t)k*NTOT + cbase + q*4);
      float v[4] = {sgn*fabsf(w.x), sgn*fabsf(w.y), sgn*fabsf(w.z), sgn*fabsf(w.w)};
      #pragma unroll
      for (int e=0;e<4;e++){
        const int n = cbase + q*4 + e;
        if (n==k || (rowSr && n<512) || (rowPfc && n>=1920 && n<2432)) v[e]=0.f;
        tile[tr][tq*16+q*4+e] = f2h(v[e]);
      }
    }
  } else {
    const float* src = w_in + (size_t)(k-NTOT)*NTOT + cbase;
    #pragma unroll
    for (int q=0;q<4;q++){
      float4 w = *(const float4*)(src + q*4);
      tile[tr][tq*16+q*4+0] = f2h(w.x);
      tile[tr][tq*16+q*4+1] = f2h(w.y);
      tile[tr][tq*16+q*4+2] = f2h(w.z);
      tile[tr][tq*16+q*4+3] = f2h(w.w);
    }
  }
  __syncthreads();
  const int n  = n0 + tr;
  const int kq = tq*16;
  uint u[8];
  #pragma unroll
  for (int q=0;q<8;q++)
    u[q] = (uint)tile[kq+2*q][tr] | ((uint)tile[kq+2*q+1][tr] << 16);
  uint4* dst = (uint4*)(WT + (size_t)n*KP + k0 + kq);
  dst[0] = make_uint4(u[0],u[1],u[2],u[3]);
  dst[1] = make_uint4(u[4],u[5],u[6],u[7]);
}

// ---------- init: h=0, ime=0, r0[b][k] ----------
__global__ void k_init(const float* __restrict__ x, ushort* __restrict__ r0,
                       float* __restrict__ h, float* __restrict__ ime){
  int i = blockIdx.x*blockDim.x + threadIdx.x;
  int nthr = gridDim.x*blockDim.x;
  for (int e=i; e<BATCH*NTOT; e+=nthr) h[e]=0.f;
  for (int e=i; e<BATCH*1024; e+=nthr) ime[e]=0.f;
  for (int e=i; e<BATCH*KP; e+=nthr){
    int b = e / KP, k = e % KP;
    float v = (k<NTOT) ? (is_dend(k)?0.5f:0.f) : x[b*NIN + (k-NTOT)];
    r0[e] = f2h(v);
  }
}

// ---------- fused step: full-K matmul for 32 cols + update, one WG per col-tile ----------
// 120 WGs x 256 thr (4 waves). Wave kw: K-chunk of 992. LDS-reduce -> pre tile ->
// couplings/mGluR/leak/rates -> rnext. WG 119 also does readout + x staging.
__global__ __launch_bounds__(256) void k_step(
    const ushort* __restrict__ WTu, const ushort* __restrict__ rcu,
    ushort* __restrict__ rnu, float* __restrict__ h, float* __restrict__ ime,
    const float* __restrict__ bvec, const float* __restrict__ d2s,
    const float* __restrict__ noise_t, const float* __restrict__ x_next,
    const float* __restrict__ w_out, const float* __restrict__ b_out,
    float* __restrict__ out_t, int hasNext)
{
  __shared__ f32x4 red[3][4][64];          // 12 KB: waves 1-3 partial accs
  __shared__ float pre_lds[32][32];        // 4 KB: [batch][col]
  const f16* WT = (const f16*)WTu;
  const f16* R  = (const f16*)rcu;
  const int bid = blockIdx.x;
  const int n0 = bid*32;
  const int tid = threadIdx.x;
  const int kw = tid>>6, l = tid&63;
  const int l15 = l&15, lh = l>>4;

  f32x4 acc[2][2];
  #pragma unroll
  for (int m=0;m<2;m++)
    #pragma unroll
    for (int f=0;f<2;f++){ acc[m][f].x=0;acc[m][f].y=0;acc[m][f].z=0;acc[m][f].w=0; }

  {
    const int kbase = kw*992 + lh*8;
    const f16* pa0 = R  + (size_t)l15*KP + kbase;
    const f16* pa1 = pa0 + (size_t)16*KP;
    const f16* pb0 = WT + (size_t)(n0+l15)*KP + kbase;
    const f16* pb1 = pb0 + (size_t)16*KP;
    #pragma unroll 4
    for (int ks=0; ks<31; ks++){
      const int ko = ks*32;
      f16x8 a0 = *(const f16x8*)(pa0 + ko);
      f16x8 a1 = *(const f16x8*)(pa1 + ko);
      f16x8 b0 = *(const f16x8*)(pb0 + ko);
      f16x8 b1 = *(const f16x8*)(pb1 + ko);
      acc[0][0] = __builtin_amdgcn_mfma_f32_16x16x32_f16(a0, b0, acc[0][0], 0,0,0);
      acc[0][1] = __builtin_amdgcn_mfma_f32_16x16x32_f16(a0, b1, acc[0][1], 0,0,0);
      acc[1][0] = __builtin_amdgcn_mfma_f32_16x16x32_f16(a1, b0, acc[1][0], 0,0,0);
      acc[1][1] = __builtin_amdgcn_mfma_f32_16x16x32_f16(a1, b1, acc[1][1], 0,0,0);
    }
  }

  if (kw > 0){
    #pragma unroll
    for (int m=0;m<2;m++)
      #pragma unroll
      for (int f=0;f<2;f++) red[kw-1][m*2+f][l] = acc[m][f];
  }
  __syncthreads();
  if (kw == 0){
    #pragma unroll
    for (int w=0;w<3;w++)
      #pragma unroll
      for (int m=0;m<2;m++)
        #pragma unroll
        for (int f=0;f<2;f++) acc[m][f] += red[w][m*2+f][l];
    // C-frag layout: col = nf*16 + (l&15), row(batch) = m*16 + (l>>4)*4 + reg
    #pragma unroll
    for (int m=0;m<2;m++)
      #pragma unroll
      for (int f=0;f<2;f++)
        #pragma unroll
        for (int rg=0;rg<4;rg++)
          pre_lds[m*16 + lh*4 + rg][f*16 + l15] = acc[m][f][rg];
  }
  __syncthreads();

  // ---- update: thread -> (batch ub, 4 consecutive cols uc) ----
  {
    const int ub = tid>>3;
    const int uc = (tid&7)*4;
    const int n  = n0 + uc;
    const float NS = 0.0063245553203367585f;         // sqrt(2*0.2)*0.01
    const float LN10 = 2.302585092994046f;
    const float CEXP = 1.6989700043360187f/511.0f;   // (log10(5000)-2)/511

    float4 pv = *(const float4*)&pre_lds[ub][uc];
    float p[4] = {pv.x, pv.y, pv.z, pv.w};
    #pragma unroll
    for (int j=0;j<4;j++) p[j] += bvec[n+j];

    if (n0 < 512){                                   // SR dend -> SR E soma
      #pragma unroll
      for (int j=0;j<4;j++){
        const int nn = n+j;
        p[j] += h2f(rcu[ub*KP + 512 +nn])*d2s[nn]
              + h2f(rcu[ub*KP + 1024+nn])*d2s[512+nn];
      }
    } else if (n0 >= 1920 && n0 < 2432){             // PFC dend -> PFC E soma
      #pragma unroll
      for (int j=0;j<4;j++){
        const int jj = n+j-1920;
        p[j] += h2f(rcu[ub*KP + 2432+jj])*d2s[1024+jj]
              + h2f(rcu[ub*KP + 2944+jj])*d2s[1536+jj];
      }
    }
    if (n0 >= 2432 && n0 < 3456){                    // mGluR on PFC E dend
      float4 im4 = *(const float4*)&ime[ub*1024 + (n-2432)];
      float im[4] = {im4.x, im4.y, im4.z, im4.w};
      #pragma unroll
      for (int j=0;j<4;j++){
        const int jj = n+j-2432;
        const float alpha = expf(-LN10*(1.0f + CEXP*(float)(jj & 511)));
        const float imn = (1.f-alpha)*im[j] + alpha*fmaxf(p[j],0.f);
        im[j] = imn; p[j] += imn;
      }
      float4 st = {im[0],im[1],im[2],im[3]};
      *(float4*)&ime[ub*1024 + (n-2432)] = st;
    }
    float4 h4 = *(const float4*)&h[ub*NTOT + n];
    float4 nz = *(const float4*)&noise_t[ub*NTOT + n];
    float hh[4] = {h4.x,h4.y,h4.z,h4.w};
    float nzz[4] = {nz.x,nz.y,nz.z,nz.w};
    const bool dend = is_dend(n0);                   // region-uniform per 32-col tile
    ushort rv[4];
    #pragma unroll
    for (int j=0;j<4;j++){
      const float hn = 0.8f*hh[j] + 0.2f*p[j] + NS*nzz[j];
      hh[j] = hn;
      rv[j] = f2h(dend ? (1.f/(1.f+expf(-hn))) : fmaxf(hn,0.f));
    }
    float4 hst = {hh[0],hh[1],hh[2],hh[3]};
    *(float4*)&h[ub*NTOT + n] = hst;
    ushort4 rst = {rv[0],rv[1],rv[2],rv[3]};
    *(ushort4*)&rnu[ub*KP + n] = rst;
  }

  // ---- WG 119: readout (uses rcur) + next-x staging ----
  if (bid == 119){
    if (kw < 3){
      const int o = kw, b = l>>1, half = l&1;
      const f16* rr = R + (size_t)b*KP + half*256;
      float s = 0.f;
      #pragma unroll 8
      for (int k2=0;k2<256;k2++) s += (float)rr[k2] * w_out[(half*256+k2)*3+o];
      s += __shfl_down(s, 1);
      if (half==0) out_t[b*3+o] = s + b_out[o];
    }
    if (hasNext){
      const int b = tid>>3, j = (tid&7)*16;
      const float* xs = x_next + b*NIN + j;
      #pragma unroll
      for (int q=0;q<4;q++){
        float4 v = *(const float4*)(xs + q*4);
        ushort4 st = {f2h(v.x),f2h(v.y),f2h(v.z),f2h(v.w)};
        *(ushort4*)&rnu[b*KP + NTOT + j + q*4] = st;
      }
    }
  }
}

extern "C" void kernel_launch(void* const* d_in, const int* in_sizes, int n_in,
                              void* d_out, int out_size, void* d_ws, size_t ws_size,
                              hipStream_t stream) {
  const float* x     = (const float*)d_in[0];   // [100,32,128]
  const float* noise = (const float*)d_in[1];   // [100,32,3840]
  const float* w_rec = (const float*)d_in[2];   // [3840,3840]
  const float* w_in  = (const float*)d_in[3];   // [128,3840]
  const float* bvec  = (const float*)d_in[4];   // [3840]
  const float* d2s   = (const float*)d_in[5];   // [2048]
  const float* w_out = (const float*)d_in[6];   // [512,3]
  const float* b_out = (const float*)d_in[7];   // [3]
  // d_in[8] = mask: derived analytically
  float* out = (float*)d_out;                   // [100,32,3]

  char* ws = (char*)d_ws;
  ushort* WT  = (ushort*)(ws);                  // 30,474,240 B
  ushort* r0  = (ushort*)(ws + 30474240);       //    253,952 B
  ushort* r1  = (ushort*)(ws + 30728192);       //    253,952 B
  float*  h   = (float*)(ws + 30982144);        //    491,520 B
  float*  ime = (float*)(ws + 31473664);        //    131,072 B

  k_prep_w<<<3720,256,0,stream>>>(w_rec, w_in, WT);
  k_init<<<64,256,0,stream>>>(x, r0, h, ime);
  for (int t=0; t<TSTEPS; t++){
    ushort* rc = (t&1) ? r1 : r0;
    ushort* rn = (t&1) ? r0 : r1;
    const int hasNext = (t+1<TSTEPS) ? 1 : 0;
    k_step<<<120,256,0,stream>>>(WT, rc, rn, h, ime, bvec, d2s,
        noise + (size_t)t*BATCH*NTOT,
        x + (size_t)(hasNext ? (t+1) : t)*BATCH*NIN,
        w_out, b_out,
        out + (size_t)t*BATCH*3,
        hasNext);
  }
}